// Round 2
// baseline (216.145 us; speedup 1.0000x reference)
//
#include <hip/hip_runtime.h>
#include <hip/hip_bf16.h>

// Problem constants
#define B_ 8
#define C_ 64
#define N_ 4096
#define K_ 16
#define E_ 64
#define EPSBN 1e-5f
#define CNT1 524288.0f   // B*N*K
#define CNT3 32768.0f    // B*N

typedef short v8s __attribute__((ext_vector_type(8)));
typedef float v16f __attribute__((ext_vector_type(16)));

__device__ __forceinline__ unsigned short f2bf(float f) {
  union { float f; unsigned u; } v; v.f = f;
  unsigned u = v.u;
  u += 0x7fffu + ((u >> 16) & 1u);   // RNE
  return (unsigned short)(u >> 16);
}
__device__ __forceinline__ float bf2f(unsigned short s) {
  union { unsigned u; float f; } v; v.u = ((unsigned)s) << 16;
  return v.f;
}

// ---------------------------------------------------------------------------
// K0: transpose x (B,C,N)->xT (B,N,C) fp32, and cast W1/W2/W3 to bf16
// ---------------------------------------------------------------------------
__global__ void prep_kernel(const float* __restrict__ x,
                            const float* __restrict__ W1,
                            const float* __restrict__ W2,
                            const float* __restrict__ W3,
                            float* __restrict__ xT,
                            unsigned short* __restrict__ Wbf) {
  __shared__ float tile[64][65];
  int blk = blockIdx.x;
  int t = threadIdx.x;
  if (blk >= 512) {  // weight cast: 3*4096 elements
    int i = (blk - 512) * 256 + t;
    int w = i >> 12;
    const float* src = (w == 0) ? W1 : (w == 1) ? W2 : W3;
    Wbf[i] = f2bf(src[i & 4095]);
    return;
  }
  int b = blk >> 6;
  int n0 = (blk & 63) << 6;
  int tn = t & 63, cg = t >> 6;
  for (int i = 0; i < 16; ++i) {
    int c = cg * 16 + i;
    tile[c][tn] = x[(((size_t)(b * 64 + c)) << 12) + n0 + tn];
  }
  __syncthreads();
  int r = t >> 2, q = t & 3;
  float4* dst = (float4*)(xT + (((size_t)((b << 12) + n0 + r)) << 6) + q * 16);
  for (int ii = 0; ii < 4; ++ii) {
    float4 v;
    v.x = tile[q * 16 + ii * 4 + 0][r];
    v.y = tile[q * 16 + ii * 4 + 1][r];
    v.z = tile[q * 16 + ii * 4 + 2][r];
    v.w = tile[q * 16 + ii * 4 + 3][r];
    dst[ii] = v;
  }
}

// ---------------------------------------------------------------------------
// P1: gather + edge + GEMM1, stats1 only. Per-wave 32-edge tiles.
// A-fragments built directly in registers from the gather (no LDS, no
// barriers in the loop). C layout: lane = out-channel (fixed!), regs = edges.
// ---------------------------------------------------------------------------
__global__ __launch_bounds__(256) void p1_stats(
    const float* __restrict__ xT, const int* __restrict__ idx,
    const unsigned short* __restrict__ Wb, float* __restrict__ stats) {
  __shared__ float bs[64], bq[64];
  int t = threadIdx.x;
  if (t < 64) { bs[t] = 0.f; bq[t] = 0.f; }
  __syncthreads();
  int lane = t & 63, wid = t >> 6;
  int l31 = lane & 31, lh = lane >> 5;
  v8s w[2][4];
#pragma unroll
  for (int s = 0; s < 2; ++s)
#pragma unroll
    for (int ks = 0; ks < 4; ++ks)
      w[s][ks] = *((const v8s*)(Wb + (s * 32 + l31) * 64 + ks * 16 + lh * 8));
  float ss0 = 0.f, sq0 = 0.f, ss1 = 0.f, sq1 = 0.f;
  int nw = gridDim.x * 4;
  for (int tile = blockIdx.x * 4 + wid; tile < 16384; tile += nw) {
    int p = (tile << 5) + l31;
    int j = idx[p];
    int site = p >> 4;
    int b = p >> 16;
    const float* nrow = xT + (((size_t)((b << 12) + j)) << 6) + lh * 8;
    const float* crow = xT + (((size_t)site) << 6) + lh * 8;
    v16f a0, a1;
#pragma unroll
    for (int i = 0; i < 16; ++i) { a0[i] = 0.f; a1[i] = 0.f; }
#pragma unroll
    for (int ks = 0; ks < 4; ++ks) {
      float4 n0 = *((const float4*)(nrow + ks * 16));
      float4 n1 = *((const float4*)(nrow + ks * 16 + 4));
      float4 c0 = *((const float4*)(crow + ks * 16));
      float4 c1 = *((const float4*)(crow + ks * 16 + 4));
      v8s af;
      unsigned* au = (unsigned*)&af;
      au[0] = (unsigned)f2bf(n0.x - c0.x) | ((unsigned)f2bf(n0.y - c0.y) << 16);
      au[1] = (unsigned)f2bf(n0.z - c0.z) | ((unsigned)f2bf(n0.w - c0.w) << 16);
      au[2] = (unsigned)f2bf(n1.x - c1.x) | ((unsigned)f2bf(n1.y - c1.y) << 16);
      au[3] = (unsigned)f2bf(n1.z - c1.z) | ((unsigned)f2bf(n1.w - c1.w) << 16);
      a0 = __builtin_amdgcn_mfma_f32_32x32x16_bf16(af, w[0][ks], a0, 0, 0, 0);
      a1 = __builtin_amdgcn_mfma_f32_32x32x16_bf16(af, w[1][ks], a1, 0, 0, 0);
    }
#pragma unroll
    for (int i = 0; i < 16; ++i) {
      ss0 += a0[i]; sq0 += a0[i] * a0[i];
      ss1 += a1[i]; sq1 += a1[i] * a1[i];
    }
  }
  ss0 += __shfl_xor(ss0, 32); sq0 += __shfl_xor(sq0, 32);
  ss1 += __shfl_xor(ss1, 32); sq1 += __shfl_xor(sq1, 32);
  if (lh == 0) {
    atomicAdd(&bs[l31], ss0); atomicAdd(&bq[l31], sq0);
    atomicAdd(&bs[32 + l31], ss1); atomicAdd(&bq[32 + l31], sq1);
  }
  __syncthreads();
  if (t < 64) atomicAdd(&stats[t], bs[t]);
  else if (t < 128) atomicAdd(&stats[t], bq[t - 64]);
}

// ---------------------------------------------------------------------------
// P2: recompute GEMM1, BN1+ReLU (lane-constant affine), wave-private LDS
// transpose, GEMM2, stats2, and per-site min/max over the 16 neighbors
// (writes only (B*N,64) min and max fp32 = 16 MB). No barriers in the loop.
// ---------------------------------------------------------------------------
__global__ __launch_bounds__(256) void p2_gemm12(
    const float* __restrict__ xT, const int* __restrict__ idx,
    const unsigned short* __restrict__ Wb,  // W1 at 0, W2 at 4096
    const float* __restrict__ g1, const float* __restrict__ be1,
    float* __restrict__ h2mn, float* __restrict__ h2mx,
    float* __restrict__ stats) {
  __shared__ unsigned short slab[4][32 * 72];
  __shared__ float bs[64], bq[64], lA[64], lC[64];
  int t = threadIdx.x;
  if (t < 64) {
    bs[t] = 0.f; bq[t] = 0.f;
    float mean = stats[t] / CNT1;
    float var = stats[64 + t] / CNT1 - mean * mean;
    float a = g1[t] * rsqrtf(var + EPSBN);
    lA[t] = a; lC[t] = be1[t] - mean * a;
  }
  __syncthreads();
  int lane = t & 63, wid = t >> 6;
  int l31 = lane & 31, lh = lane >> 5;
  v8s w1[2][4], w2[2][4];
#pragma unroll
  for (int s = 0; s < 2; ++s)
#pragma unroll
    for (int ks = 0; ks < 4; ++ks) {
      w1[s][ks] = *((const v8s*)(Wb + (s * 32 + l31) * 64 + ks * 16 + lh * 8));
      w2[s][ks] = *((const v8s*)(Wb + 4096 + (s * 32 + l31) * 64 + ks * 16 + lh * 8));
    }
  float a0c = lA[l31], c0c = lC[l31];
  float a1c = lA[32 + l31], c1c = lC[32 + l31];
  unsigned short* myslab = slab[wid];
  float ss0 = 0.f, sq0 = 0.f, ss1 = 0.f, sq1 = 0.f;
  int nw = gridDim.x * 4;
  for (int tile = blockIdx.x * 4 + wid; tile < 16384; tile += nw) {
    int p = (tile << 5) + l31;
    int j = idx[p];
    int site = p >> 4;
    int b = p >> 16;
    const float* nrow = xT + (((size_t)((b << 12) + j)) << 6) + lh * 8;
    const float* crow = xT + (((size_t)site) << 6) + lh * 8;
    v16f a0, a1;
#pragma unroll
    for (int i = 0; i < 16; ++i) { a0[i] = 0.f; a1[i] = 0.f; }
#pragma unroll
    for (int ks = 0; ks < 4; ++ks) {
      float4 n0 = *((const float4*)(nrow + ks * 16));
      float4 n1 = *((const float4*)(nrow + ks * 16 + 4));
      float4 c0 = *((const float4*)(crow + ks * 16));
      float4 c1 = *((const float4*)(crow + ks * 16 + 4));
      v8s af;
      unsigned* au = (unsigned*)&af;
      au[0] = (unsigned)f2bf(n0.x - c0.x) | ((unsigned)f2bf(n0.y - c0.y) << 16);
      au[1] = (unsigned)f2bf(n0.z - c0.z) | ((unsigned)f2bf(n0.w - c0.w) << 16);
      au[2] = (unsigned)f2bf(n1.x - c1.x) | ((unsigned)f2bf(n1.y - c1.y) << 16);
      au[3] = (unsigned)f2bf(n1.z - c1.z) | ((unsigned)f2bf(n1.w - c1.w) << 16);
      a0 = __builtin_amdgcn_mfma_f32_32x32x16_bf16(af, w1[0][ks], a0, 0, 0, 0);
      a1 = __builtin_amdgcn_mfma_f32_32x32x16_bf16(af, w1[1][ks], a1, 0, 0, 0);
    }
    // BN1 + ReLU (lane-constant affine), pack into wave-private slab [edge][ch]
#pragma unroll
    for (int i = 0; i < 16; ++i) {
      int e = (i & 3) + ((i >> 2) << 3) + (lh << 2);
      float r0 = fmaxf(a0[i] * a0c + c0c, 0.f);
      float r1 = fmaxf(a1[i] * a1c + c1c, 0.f);
      myslab[e * 72 + l31] = f2bf(r0);
      myslab[e * 72 + 32 + l31] = f2bf(r1);
    }
    // GEMM2: A = slab rows (intra-wave lgkmcnt ordering; slab is wave-private)
    v16f b0, b1;
#pragma unroll
    for (int i = 0; i < 16; ++i) { b0[i] = 0.f; b1[i] = 0.f; }
#pragma unroll
    for (int ks = 0; ks < 4; ++ks) {
      v8s af = *((const v8s*)(myslab + l31 * 72 + ks * 16 + lh * 8));
      b0 = __builtin_amdgcn_mfma_f32_32x32x16_bf16(af, w2[0][ks], b0, 0, 0, 0);
      b1 = __builtin_amdgcn_mfma_f32_32x32x16_bf16(af, w2[1][ks], b1, 0, 0, 0);
    }
    // stats2 + per-site min/max (site0 = regs 0..7, site1 = regs 8..15)
    float mx00 = b0[0], mn00 = b0[0], mx01 = b0[8], mn01 = b0[8];
    float mx10 = b1[0], mn10 = b1[0], mx11 = b1[8], mn11 = b1[8];
#pragma unroll
    for (int i = 0; i < 16; ++i) {
      ss0 += b0[i]; sq0 += b0[i] * b0[i];
      ss1 += b1[i]; sq1 += b1[i] * b1[i];
    }
#pragma unroll
    for (int i = 1; i < 8; ++i) {
      mx00 = fmaxf(mx00, b0[i]); mn00 = fminf(mn00, b0[i]);
      mx01 = fmaxf(mx01, b0[8 + i]); mn01 = fminf(mn01, b0[8 + i]);
      mx10 = fmaxf(mx10, b1[i]); mn10 = fminf(mn10, b1[i]);
      mx11 = fmaxf(mx11, b1[8 + i]); mn11 = fminf(mn11, b1[8 + i]);
    }
    mx00 = fmaxf(mx00, __shfl_xor(mx00, 32)); mn00 = fminf(mn00, __shfl_xor(mn00, 32));
    mx01 = fmaxf(mx01, __shfl_xor(mx01, 32)); mn01 = fminf(mn01, __shfl_xor(mn01, 32));
    mx10 = fmaxf(mx10, __shfl_xor(mx10, 32)); mn10 = fminf(mn10, __shfl_xor(mn10, 32));
    mx11 = fmaxf(mx11, __shfl_xor(mx11, 32)); mn11 = fminf(mn11, __shfl_xor(mn11, 32));
    int s2 = tile << 1;
    if (lh == 0) {
      h2mn[(s2 + 0) * 64 + l31] = mn00;
      h2mn[(s2 + 1) * 64 + l31] = mn01;
      h2mn[(s2 + 0) * 64 + 32 + l31] = mn10;
      h2mn[(s2 + 1) * 64 + 32 + l31] = mn11;
    } else {
      h2mx[(s2 + 0) * 64 + l31] = mx00;
      h2mx[(s2 + 1) * 64 + l31] = mx01;
      h2mx[(s2 + 0) * 64 + 32 + l31] = mx10;
      h2mx[(s2 + 1) * 64 + 32 + l31] = mx11;
    }
  }
  ss0 += __shfl_xor(ss0, 32); sq0 += __shfl_xor(sq0, 32);
  ss1 += __shfl_xor(ss1, 32); sq1 += __shfl_xor(sq1, 32);
  if (lh == 0) {
    atomicAdd(&bs[l31], ss0); atomicAdd(&bq[l31], sq0);
    atomicAdd(&bs[32 + l31], ss1); atomicAdd(&bq[32 + l31], sq1);
  }
  __syncthreads();
  if (t < 64) atomicAdd(&stats[128 + t], bs[t]);
  else if (t < 128) atomicAdd(&stats[192 + (t - 64)], bq[t - 64]);
}

// ---------------------------------------------------------------------------
// P3: BN2 via sign-select on min/max, ReLU, GEMM3 -> h3 (fp32), stats3
// ---------------------------------------------------------------------------
__global__ __launch_bounds__(256, 2) void p3_gemm3(
    const unsigned short* __restrict__ Wb,  // W3
    const float* __restrict__ h2mn, const float* __restrict__ h2mx,
    const float* __restrict__ g2, const float* __restrict__ be2,
    float* __restrict__ h3, float* __restrict__ stats) {
  __shared__ uint4 ldsA[64 * 9];
  __shared__ float bs[64], bq[64], lA[64], lC[64];
  int t = threadIdx.x;
  if (t < 64) {
    bs[t] = 0.f; bq[t] = 0.f;
    float mean = stats[128 + t] / CNT1;
    float var = stats[192 + t] / CNT1 - mean * mean;
    float a = g2[t] * rsqrtf(var + EPSBN);
    lA[t] = a; lC[t] = be2[t] - mean * a;
  }
  __syncthreads();
  int lane = t & 63, wid = t >> 6;
  int rb = wid & 1, ctile = wid >> 1;
  int l31 = lane & 31, lh = lane >> 5;
  int o = ctile * 32 + l31;
  v8s wf[4];
#pragma unroll
  for (int ks = 0; ks < 4; ++ks)
    wf[ks] = *((const v8s*)(Wb + o * 64 + ks * 16 + lh * 8));
  int r = t >> 2, q = t & 3;
  int arow = rb * 32 + l31;
  int s0 = blockIdx.x << 6;
  {
    int site = s0 + r;
    float aa[16], cc[16];
#pragma unroll
    for (int i = 0; i < 16; ++i) { aa[i] = lA[q * 16 + i]; cc[i] = lC[q * 16 + i]; }
    const float4* mn4 = (const float4*)(h2mn + site * 64 + q * 16);
    const float4* mx4 = (const float4*)(h2mx + site * 64 + q * 16);
    float mnv[16], mxv[16];
#pragma unroll
    for (int ii = 0; ii < 4; ++ii) {
      float4 a = mn4[ii];
      mnv[ii * 4 + 0] = a.x; mnv[ii * 4 + 1] = a.y; mnv[ii * 4 + 2] = a.z; mnv[ii * 4 + 3] = a.w;
      float4 b = mx4[ii];
      mxv[ii * 4 + 0] = b.x; mxv[ii * 4 + 1] = b.y; mxv[ii * 4 + 2] = b.z; mxv[ii * 4 + 3] = b.w;
    }
    uint4 ch2[2];
    unsigned* cu = (unsigned*)ch2;
#pragma unroll
    for (int ii = 0; ii < 8; ++ii) {
      float s0v = (aa[2 * ii] > 0.f) ? mxv[2 * ii] : mnv[2 * ii];
      float s1v = (aa[2 * ii + 1] > 0.f) ? mxv[2 * ii + 1] : mnv[2 * ii + 1];
      float v0 = fmaxf(aa[2 * ii] * s0v + cc[2 * ii], 0.f);
      float v1 = fmaxf(aa[2 * ii + 1] * s1v + cc[2 * ii + 1], 0.f);
      cu[ii] = (unsigned)f2bf(v0) | ((unsigned)f2bf(v1) << 16);
    }
    ldsA[r * 9 + q * 2 + 0] = ch2[0];
    ldsA[r * 9 + q * 2 + 1] = ch2[1];
  }
  __syncthreads();
  v16f acc;
#pragma unroll
  for (int i = 0; i < 16; ++i) acc[i] = 0.f;
#pragma unroll
  for (int ks = 0; ks < 4; ++ks) {
    v8s a = *((const v8s*)&ldsA[arow * 9 + ks * 2 + lh]);
    acc = __builtin_amdgcn_mfma_f32_32x32x16_bf16(a, wf[ks], acc, 0, 0, 0);
  }
  float ssum = 0.f, ssq = 0.f;
#pragma unroll
  for (int i = 0; i < 16; ++i) {
    float v = acc[i];
    ssum += v; ssq += v * v;
    int row = (i & 3) + ((i >> 2) << 3) + (lh << 2);
    h3[(((size_t)(s0 + rb * 32 + row)) << 6) + o] = v;
  }
  ssum += __shfl_xor(ssum, 32);
  ssq += __shfl_xor(ssq, 32);
  if (lh == 0) { atomicAdd(&bs[o], ssum); atomicAdd(&bq[o], ssq); }
  __syncthreads();
  if (t < 64) atomicAdd(&stats[256 + t], bs[t]);
  else if (t < 128) atomicAdd(&stats[320 + (t - 64)], bq[t - 64]);
}

// ---------------------------------------------------------------------------
// K4: BN3+ReLU, transpose (B,N,E)->(B,E,N), write out
// ---------------------------------------------------------------------------
__global__ void k4_out(const float* __restrict__ h3,
                       const float* __restrict__ g3, const float* __restrict__ be3,
                       float* __restrict__ out, const float* __restrict__ stats) {
  __shared__ float lA[64], lC[64];
  __shared__ float tile[64][65];
  int t = threadIdx.x;
  if (t < 64) {
    float mean = stats[256 + t] / CNT3;
    float var = stats[320 + t] / CNT3 - mean * mean;
    float a = g3[t] * rsqrtf(var + EPSBN);
    lA[t] = a; lC[t] = be3[t] - mean * a;
  }
  __syncthreads();
  int blk = blockIdx.x;
  int b = blk >> 6, n0 = (blk & 63) << 6;
  int r = t >> 2, q = t & 3;
  const float4* hp = (const float4*)(h3 + (((size_t)((b << 12) + n0 + r)) << 6)) + q * 4;
  for (int ii = 0; ii < 4; ++ii) {
    float4 v = hp[ii];
    int c = q * 16 + ii * 4;
    tile[c + 0][r] = fmaxf(v.x * lA[c + 0] + lC[c + 0], 0.f);
    tile[c + 1][r] = fmaxf(v.y * lA[c + 1] + lC[c + 1], 0.f);
    tile[c + 2][r] = fmaxf(v.z * lA[c + 2] + lC[c + 2], 0.f);
    tile[c + 3][r] = fmaxf(v.w * lA[c + 3] + lC[c + 3], 0.f);
  }
  __syncthreads();
  int oo = t >> 2, seg = t & 3;
  float4* dst = (float4*)(out + (((size_t)(b * 64 + oo)) << 12) + n0 + seg * 16);
  for (int ii = 0; ii < 4; ++ii) {
    float4 v;
    v.x = tile[oo][seg * 16 + ii * 4 + 0];
    v.y = tile[oo][seg * 16 + ii * 4 + 1];
    v.z = tile[oo][seg * 16 + ii * 4 + 2];
    v.w = tile[oo][seg * 16 + ii * 4 + 3];
    dst[ii] = v;
  }
}

// ---------------------------------------------------------------------------
extern "C" void kernel_launch(void* const* d_in, const int* in_sizes, int n_in,
                              void* d_out, int out_size, void* d_ws, size_t ws_size,
                              hipStream_t stream) {
  const float* x = (const float*)d_in[0];
  const int* idx = (const int*)d_in[1];
  const float* W1 = (const float*)d_in[2];
  const float* g1 = (const float*)d_in[4];
  const float* be1 = (const float*)d_in[5];
  const float* W2 = (const float*)d_in[6];
  const float* g2 = (const float*)d_in[8];
  const float* be2 = (const float*)d_in[9];
  const float* W3 = (const float*)d_in[10];
  const float* g3 = (const float*)d_in[12];
  const float* be3 = (const float*)d_in[13];
  float* out = (float*)d_out;

  char* ws = (char*)d_ws;
  float* xT = (float*)ws;                                     // 8 MB
  float* h2mn = (float*)(ws + (8u << 20));                    // 8 MB
  float* h2mx = (float*)(ws + (16u << 20));                   // 8 MB
  float* h3 = (float*)(ws + (24u << 20));                     // 8 MB
  unsigned short* Wbf = (unsigned short*)(ws + (32u << 20));  // 24 KB
  float* stats = (float*)(ws + (32u << 20) + (32u << 10));    // 384 floats

  hipMemsetAsync(stats, 0, 384 * sizeof(float), stream);
  prep_kernel<<<560, 256, 0, stream>>>(x, W1, W2, W3, xT, Wbf);
  p1_stats<<<1024, 256, 0, stream>>>(xT, idx, Wbf, stats);
  p2_gemm12<<<1024, 256, 0, stream>>>(xT, idx, Wbf, g1, be1, h2mn, h2mx, stats);
  p3_gemm3<<<512, 256, 0, stream>>>(Wbf + 8192, h2mn, h2mx, g2, be2, h3, stats);
  k4_out<<<512, 256, 0, stream>>>(h3, g3, be3, out, stats);
}

// Round 3
// 147.392 us; speedup vs baseline: 1.4665x; 1.4665x over previous
//
#include <hip/hip_runtime.h>

// Problem constants
#define EPSBN 1e-5f
#define CNT1 524288.0f   // B*N*K
#define CNT3 32768.0f    // B*N
#define NREP 16          // stats replicas (atomic spread)

typedef short v8s __attribute__((ext_vector_type(8)));
typedef float v16f __attribute__((ext_vector_type(16)));

__device__ __forceinline__ unsigned short f2bf(float f) {
  union { float f; unsigned u; } v; v.f = f;
  unsigned u = v.u;
  u += 0x7fffu + ((u >> 16) & 1u);   // RNE
  return (unsigned short)(u >> 16);
}
__device__ __forceinline__ unsigned pack2bf(float a, float b) {
  return (unsigned)f2bf(a) | ((unsigned)f2bf(b) << 16);
}
__device__ __forceinline__ float bflo(unsigned u) {
  union { unsigned u; float f; } v; v.u = u << 16; return v.f;
}
__device__ __forceinline__ float bfhi(unsigned u) {
  union { unsigned u; float f; } v; v.u = u & 0xffff0000u; return v.f;
}

// ---------------------------------------------------------------------------
// prep: y = W1 * x  (per point), y stored bf16 (B*N,64). Also cast W2,W3.
// Block = one (batch, 64-point) tile. Transpose x into LDS bf16, MFMA.
// ---------------------------------------------------------------------------
__global__ __launch_bounds__(256) void prep(
    const float* __restrict__ x, const float* __restrict__ W1,
    const float* __restrict__ W2, const float* __restrict__ W3,
    unsigned short* __restrict__ y, unsigned short* __restrict__ Wbf) {
  int blk = blockIdx.x, t = threadIdx.x;
  if (blk >= 512) {  // cast W2 (4096) then W3 (4096)
    int i = (blk - 512) * 256 + t;
    const float* src = (i < 4096) ? W2 : W3;
    Wbf[i] = f2bf(src[i & 4095]);
    return;
  }
  __shared__ unsigned short ldsX[64 * 72];  // [point][ch], pad 72
  int b = blk >> 6, n0 = (blk & 63) << 6;
  int tn = t & 63, cg = t >> 6;
#pragma unroll
  for (int i = 0; i < 16; ++i) {
    int c = cg * 16 + i;
    ldsX[tn * 72 + c] = f2bf(x[(((size_t)(b * 64 + c)) << 12) + n0 + tn]);
  }
  __syncthreads();
  int lane = t & 63, w = t >> 6;
  int l31 = lane & 31, lh = lane >> 5;
  int ot = w & 1, ph = w >> 1;   // o-tile, point-half
  int o = ot * 32 + l31;
  v16f acc;
#pragma unroll
  for (int i = 0; i < 16; ++i) acc[i] = 0.f;
#pragma unroll
  for (int ks = 0; ks < 4; ++ks) {
    const float* wrow = W1 + o * 64 + ks * 16 + lh * 8;
    float4 wa = *((const float4*)wrow);
    float4 wb = *((const float4*)(wrow + 4));
    v8s wf; unsigned* wu = (unsigned*)&wf;
    wu[0] = pack2bf(wa.x, wa.y); wu[1] = pack2bf(wa.z, wa.w);
    wu[2] = pack2bf(wb.x, wb.y); wu[3] = pack2bf(wb.z, wb.w);
    v8s af = *((const v8s*)&ldsX[(ph * 32 + l31) * 72 + ks * 16 + lh * 8]);
    acc = __builtin_amdgcn_mfma_f32_32x32x16_bf16(af, wf, acc, 0, 0, 0);
  }
#pragma unroll
  for (int i = 0; i < 16; ++i) {
    int row = (i & 3) + ((i >> 2) << 3) + (lh << 2);
    int pt = (b << 12) + n0 + ph * 32 + row;
    y[pt * 64 + o] = f2bf(acc[i]);
  }
}

// ---------------------------------------------------------------------------
// p1: stats1 = sum/sumsq of (y_j - y_i) over all edges. Pure gather, no MFMA.
// Lane = (edge-in-8, 8-ch chunk). Batch pinned to XCD via blk&7.
// ---------------------------------------------------------------------------
__global__ __launch_bounds__(256) void p1_stats(
    const unsigned short* __restrict__ y, const int* __restrict__ idx,
    float* __restrict__ S1) {
  __shared__ float bs[64], bq[64];
  int t = threadIdx.x;
  if (t < 64) { bs[t] = 0.f; bq[t] = 0.f; }
  __syncthreads();
  int blk = blockIdx.x;
  int batch = blk & 7, bi = blk >> 3;       // bi 0..127
  int w = t >> 6, lane = t & 63;
  int ch = (lane & 7) << 3, eg = lane >> 3;
  int ebase = (batch << 16) + bi * 512 + w * 128;
  float ss[8], sq[8];
#pragma unroll
  for (int k = 0; k < 8; ++k) { ss[k] = 0.f; sq[k] = 0.f; }
  for (int it = 0; it < 16; ++it) {
    int p = ebase + it * 8 + eg;
    int j = idx[p];
    int site = p >> 4;
    uint4 uj = *((const uint4*)(y + (((size_t)((batch << 12) + j)) << 6) + ch));
    uint4 ui = *((const uint4*)(y + (((size_t)site) << 6) + ch));
    const unsigned* aj = (const unsigned*)&uj;
    const unsigned* ai = (const unsigned*)&ui;
#pragma unroll
    for (int d = 0; d < 4; ++d) {
      float d0 = bflo(aj[d]) - bflo(ai[d]);
      float d1 = bfhi(aj[d]) - bfhi(ai[d]);
      ss[2 * d] += d0; sq[2 * d] += d0 * d0;
      ss[2 * d + 1] += d1; sq[2 * d + 1] += d1 * d1;
    }
  }
#pragma unroll
  for (int k = 0; k < 8; ++k) {
    ss[k] += __shfl_xor(ss[k], 8);  sq[k] += __shfl_xor(sq[k], 8);
    ss[k] += __shfl_xor(ss[k], 16); sq[k] += __shfl_xor(sq[k], 16);
    ss[k] += __shfl_xor(ss[k], 32); sq[k] += __shfl_xor(sq[k], 32);
  }
  if (lane < 8) {
#pragma unroll
    for (int k = 0; k < 8; ++k) {
      atomicAdd(&bs[ch + k], ss[k]);
      atomicAdd(&bq[ch + k], sq[k]);
    }
  }
  __syncthreads();
  int rep = (blk >> 3) & (NREP - 1);
  if (t < 64) atomicAdd(&S1[rep * 128 + t], bs[t]);
  else if (t < 128) atomicAdd(&S1[rep * 128 + t], bq[t - 64]);
}

// ---------------------------------------------------------------------------
// p1b: fold BN1 into u = a*y + c (neighbor side), v = a*y (center side), bf16.
// ---------------------------------------------------------------------------
__global__ __launch_bounds__(256) void p1b_uv(
    const unsigned short* __restrict__ y,
    const float* __restrict__ g1, const float* __restrict__ be1,
    const float* __restrict__ S1,
    unsigned short* __restrict__ u, unsigned short* __restrict__ v) {
  __shared__ float lA[64], lC[64];
  int t = threadIdx.x;
  if (t < 64) {
    float s = 0.f, q = 0.f;
#pragma unroll
    for (int r = 0; r < NREP; ++r) { s += S1[r * 128 + t]; q += S1[r * 128 + 64 + t]; }
    float mean = s / CNT1;
    float var = q / CNT1 - mean * mean;
    float a = g1[t] * rsqrtf(var + EPSBN);
    lA[t] = a; lC[t] = be1[t] - mean * a;
  }
  __syncthreads();
  int pt = blockIdx.x * 64 + (t >> 2);
  int cq = (t & 3) << 4;
  const uint4* yp = (const uint4*)(y + (size_t)pt * 64 + cq);
  uint4 y0 = yp[0], y1 = yp[1];
  uint4 uo[2], vo[2];
  unsigned* up = (unsigned*)uo;
  unsigned* vp = (unsigned*)vo;
#pragma unroll
  for (int d = 0; d < 8; ++d) {
    unsigned yd = (d < 4) ? ((const unsigned*)&y0)[d] : ((const unsigned*)&y1)[d - 4];
    int c = cq + 2 * d;
    float f0 = bflo(yd), f1 = bfhi(yd);
    float a0 = lA[c], a1 = lA[c + 1];
    up[d] = pack2bf(f0 * a0 + lC[c], f1 * a1 + lC[c + 1]);
    vp[d] = pack2bf(f0 * a0, f1 * a1);
  }
  uint4* ud = (uint4*)(u + (size_t)pt * 64 + cq);
  uint4* vd = (uint4*)(v + (size_t)pt * 64 + cq);
  ud[0] = uo[0]; ud[1] = uo[1];
  vd[0] = vo[0]; vd[1] = vo[1];
}

// ---------------------------------------------------------------------------
// p2: h1relu = relu(u_j - v_i) built directly as MFMA A-frags (no LDS slab),
// GEMM2 (W2), stats2, per-site min/max over K=16 -> mnb/mxb (bf16).
// ---------------------------------------------------------------------------
__global__ __launch_bounds__(256) void p2_main(
    const unsigned short* __restrict__ u, const unsigned short* __restrict__ v,
    const int* __restrict__ idx, const unsigned short* __restrict__ Wb,  // W2
    unsigned short* __restrict__ mnb, unsigned short* __restrict__ mxb,
    float* __restrict__ S2) {
  __shared__ float bs[64], bq[64];
  int t = threadIdx.x;
  if (t < 64) { bs[t] = 0.f; bq[t] = 0.f; }
  __syncthreads();
  int blk = blockIdx.x;
  int batch = blk & 7, bi = blk >> 3;   // bi 0..255
  int w = t >> 6, lane = t & 63;
  int l31 = lane & 31, lh = lane >> 5;
  v8s w2[2][4];
#pragma unroll
  for (int s = 0; s < 2; ++s)
#pragma unroll
    for (int ks = 0; ks < 4; ++ks)
      w2[s][ks] = *((const v8s*)(Wb + (s * 32 + l31) * 64 + ks * 16 + lh * 8));
  float ss0 = 0.f, sq0 = 0.f, ss1 = 0.f, sq1 = 0.f;
#pragma unroll
  for (int it = 0; it < 2; ++it) {
    int tile = bi * 8 + w * 2 + it;            // 0..2047 within batch
    int p = (batch << 16) + (tile << 5) + l31;
    int j = idx[p];
    int site = p >> 4;
    const unsigned short* ur = u + (((size_t)((batch << 12) + j)) << 6) + lh * 8;
    const unsigned short* vr = v + (((size_t)site) << 6) + lh * 8;
    v16f b0, b1;
#pragma unroll
    for (int i = 0; i < 16; ++i) { b0[i] = 0.f; b1[i] = 0.f; }
#pragma unroll
    for (int ks = 0; ks < 4; ++ks) {
      uint4 uu = *((const uint4*)(ur + ks * 16));
      uint4 vv = *((const uint4*)(vr + ks * 16));
      const unsigned* uw = (const unsigned*)&uu;
      const unsigned* vw = (const unsigned*)&vv;
      v8s af; unsigned* au = (unsigned*)&af;
#pragma unroll
      for (int d = 0; d < 4; ++d) {
        float e0 = fmaxf(bflo(uw[d]) - bflo(vw[d]), 0.f);
        float e1 = fmaxf(bfhi(uw[d]) - bfhi(vw[d]), 0.f);
        au[d] = pack2bf(e0, e1);
      }
      b0 = __builtin_amdgcn_mfma_f32_32x32x16_bf16(af, w2[0][ks], b0, 0, 0, 0);
      b1 = __builtin_amdgcn_mfma_f32_32x32x16_bf16(af, w2[1][ks], b1, 0, 0, 0);
    }
    float mx00 = b0[0], mn00 = b0[0], mx01 = b0[8], mn01 = b0[8];
    float mx10 = b1[0], mn10 = b1[0], mx11 = b1[8], mn11 = b1[8];
#pragma unroll
    for (int i = 0; i < 16; ++i) {
      ss0 += b0[i]; sq0 += b0[i] * b0[i];
      ss1 += b1[i]; sq1 += b1[i] * b1[i];
    }
#pragma unroll
    for (int i = 1; i < 8; ++i) {
      mx00 = fmaxf(mx00, b0[i]);     mn00 = fminf(mn00, b0[i]);
      mx01 = fmaxf(mx01, b0[8 + i]); mn01 = fminf(mn01, b0[8 + i]);
      mx10 = fmaxf(mx10, b1[i]);     mn10 = fminf(mn10, b1[i]);
      mx11 = fmaxf(mx11, b1[8 + i]); mn11 = fminf(mn11, b1[8 + i]);
    }
    mx00 = fmaxf(mx00, __shfl_xor(mx00, 32)); mn00 = fminf(mn00, __shfl_xor(mn00, 32));
    mx01 = fmaxf(mx01, __shfl_xor(mx01, 32)); mn01 = fminf(mn01, __shfl_xor(mn01, 32));
    mx10 = fmaxf(mx10, __shfl_xor(mx10, 32)); mn10 = fminf(mn10, __shfl_xor(mn10, 32));
    mx11 = fmaxf(mx11, __shfl_xor(mx11, 32)); mn11 = fminf(mn11, __shfl_xor(mn11, 32));
    int s2 = (batch << 12) + (tile << 1);
    if (lh == 0) {
      mnb[(size_t)(s2 + 0) * 64 + l31] = f2bf(mn00);
      mnb[(size_t)(s2 + 1) * 64 + l31] = f2bf(mn01);
      mnb[(size_t)(s2 + 0) * 64 + 32 + l31] = f2bf(mn10);
      mnb[(size_t)(s2 + 1) * 64 + 32 + l31] = f2bf(mn11);
    } else {
      mxb[(size_t)(s2 + 0) * 64 + l31] = f2bf(mx00);
      mxb[(size_t)(s2 + 1) * 64 + l31] = f2bf(mx01);
      mxb[(size_t)(s2 + 0) * 64 + 32 + l31] = f2bf(mx10);
      mxb[(size_t)(s2 + 1) * 64 + 32 + l31] = f2bf(mx11);
    }
  }
  ss0 += __shfl_xor(ss0, 32); sq0 += __shfl_xor(sq0, 32);
  ss1 += __shfl_xor(ss1, 32); sq1 += __shfl_xor(sq1, 32);
  if (lh == 0) {
    atomicAdd(&bs[l31], ss0); atomicAdd(&bq[l31], sq0);
    atomicAdd(&bs[32 + l31], ss1); atomicAdd(&bq[32 + l31], sq1);
  }
  __syncthreads();
  int rep = blk & (NREP - 1);
  if (t < 64) atomicAdd(&S2[rep * 128 + t], bs[t]);
  else if (t < 128) atomicAdd(&S2[rep * 128 + t], bq[t - 64]);
}

// ---------------------------------------------------------------------------
// p3: BN2 via sign-select on bf16 min/max, ReLU, GEMM3 (W3) -> h3 fp32, stats3
// ---------------------------------------------------------------------------
__global__ __launch_bounds__(256, 2) void p3_gemm3(
    const unsigned short* __restrict__ Wb,  // W3
    const unsigned short* __restrict__ mnb, const unsigned short* __restrict__ mxb,
    const float* __restrict__ g2, const float* __restrict__ be2,
    const float* __restrict__ S2, float* __restrict__ h3, float* __restrict__ S3) {
  __shared__ uint4 ldsA[64 * 9];
  __shared__ float bs[64], bq[64], lA[64], lC[64];
  int t = threadIdx.x;
  if (t < 64) {
    bs[t] = 0.f; bq[t] = 0.f;
    float s = 0.f, q = 0.f;
#pragma unroll
    for (int r = 0; r < NREP; ++r) { s += S2[r * 128 + t]; q += S2[r * 128 + 64 + t]; }
    float mean = s / CNT1;
    float var = q / CNT1 - mean * mean;
    float a = g2[t] * rsqrtf(var + EPSBN);
    lA[t] = a; lC[t] = be2[t] - mean * a;
  }
  __syncthreads();
  int lane = t & 63, wid = t >> 6;
  int rb = wid & 1, ctile = wid >> 1;
  int l31 = lane & 31, lh = lane >> 5;
  int o = ctile * 32 + l31;
  v8s wf[4];
#pragma unroll
  for (int ks = 0; ks < 4; ++ks)
    wf[ks] = *((const v8s*)(Wb + o * 64 + ks * 16 + lh * 8));
  int r = t >> 2, q = t & 3;
  int arow = rb * 32 + l31;
  int s0 = blockIdx.x << 6;
  {
    int site = s0 + r;
    const uint4* mnp = (const uint4*)(mnb + (size_t)site * 64 + q * 16);
    const uint4* mxp = (const uint4*)(mxb + (size_t)site * 64 + q * 16);
    uint4 m0 = mnp[0], m1 = mnp[1], x0 = mxp[0], x1 = mxp[1];
    uint4 ch2[2];
    unsigned* cu = (unsigned*)ch2;
#pragma unroll
    for (int d = 0; d < 8; ++d) {
      unsigned md = (d < 4) ? ((const unsigned*)&m0)[d] : ((const unsigned*)&m1)[d - 4];
      unsigned xd = (d < 4) ? ((const unsigned*)&x0)[d] : ((const unsigned*)&x1)[d - 4];
      int c = q * 16 + 2 * d;
      float a0 = lA[c], a1 = lA[c + 1];
      float s0v = (a0 > 0.f) ? bflo(xd) : bflo(md);
      float s1v = (a1 > 0.f) ? bfhi(xd) : bfhi(md);
      float v0 = fmaxf(a0 * s0v + lC[c], 0.f);
      float v1 = fmaxf(a1 * s1v + lC[c + 1], 0.f);
      cu[d] = pack2bf(v0, v1);
    }
    ldsA[r * 9 + q * 2 + 0] = ch2[0];
    ldsA[r * 9 + q * 2 + 1] = ch2[1];
  }
  __syncthreads();
  v16f acc;
#pragma unroll
  for (int i = 0; i < 16; ++i) acc[i] = 0.f;
#pragma unroll
  for (int ks = 0; ks < 4; ++ks) {
    v8s a = *((const v8s*)&ldsA[arow * 9 + ks * 2 + lh]);
    acc = __builtin_amdgcn_mfma_f32_32x32x16_bf16(a, wf[ks], acc, 0, 0, 0);
  }
  float ssum = 0.f, ssq = 0.f;
#pragma unroll
  for (int i = 0; i < 16; ++i) {
    float vv = acc[i];
    ssum += vv; ssq += vv * vv;
    int row = (i & 3) + ((i >> 2) << 3) + (lh << 2);
    h3[(((size_t)(s0 + rb * 32 + row)) << 6) + o] = vv;
  }
  ssum += __shfl_xor(ssum, 32);
  ssq += __shfl_xor(ssq, 32);
  if (lh == 0) { atomicAdd(&bs[o], ssum); atomicAdd(&bq[o], ssq); }
  __syncthreads();
  int rep = blockIdx.x & (NREP - 1);
  if (t < 64) atomicAdd(&S3[rep * 128 + t], bs[t]);
  else if (t < 128) atomicAdd(&S3[rep * 128 + t], bq[t - 64]);
}

// ---------------------------------------------------------------------------
// k4: BN3+ReLU, transpose (B,N,E)->(B,E,N), write out
// ---------------------------------------------------------------------------
__global__ void k4_out(const float* __restrict__ h3,
                       const float* __restrict__ g3, const float* __restrict__ be3,
                       float* __restrict__ out, const float* __restrict__ S3) {
  __shared__ float lA[64], lC[64];
  __shared__ float tile[64][65];
  int t = threadIdx.x;
  if (t < 64) {
    float s = 0.f, q = 0.f;
#pragma unroll
    for (int r = 0; r < NREP; ++r) { s += S3[r * 128 + t]; q += S3[r * 128 + 64 + t]; }
    float mean = s / CNT3;
    float var = q / CNT3 - mean * mean;
    float a = g3[t] * rsqrtf(var + EPSBN);
    lA[t] = a; lC[t] = be3[t] - mean * a;
  }
  __syncthreads();
  int blk = blockIdx.x;
  int b = blk >> 6, n0 = (blk & 63) << 6;
  int r = t >> 2, q = t & 3;
  const float4* hp = (const float4*)(h3 + (((size_t)((b << 12) + n0 + r)) << 6)) + q * 4;
#pragma unroll
  for (int ii = 0; ii < 4; ++ii) {
    float4 v = hp[ii];
    int c = q * 16 + ii * 4;
    tile[c + 0][r] = fmaxf(v.x * lA[c + 0] + lC[c + 0], 0.f);
    tile[c + 1][r] = fmaxf(v.y * lA[c + 1] + lC[c + 1], 0.f);
    tile[c + 2][r] = fmaxf(v.z * lA[c + 2] + lC[c + 2], 0.f);
    tile[c + 3][r] = fmaxf(v.w * lA[c + 3] + lC[c + 3], 0.f);
  }
  __syncthreads();
  int oo = t >> 2, seg = t & 3;
  float4* dst = (float4*)(out + (((size_t)(b * 64 + oo)) << 12) + n0 + seg * 16);
#pragma unroll
  for (int ii = 0; ii < 4; ++ii) {
    float4 v;
    v.x = tile[oo][seg * 16 + ii * 4 + 0];
    v.y = tile[oo][seg * 16 + ii * 4 + 1];
    v.z = tile[oo][seg * 16 + ii * 4 + 2];
    v.w = tile[oo][seg * 16 + ii * 4 + 3];
    dst[ii] = v;
  }
}

// ---------------------------------------------------------------------------
extern "C" void kernel_launch(void* const* d_in, const int* in_sizes, int n_in,
                              void* d_out, int out_size, void* d_ws, size_t ws_size,
                              hipStream_t stream) {
  const float* x = (const float*)d_in[0];
  const int* idx = (const int*)d_in[1];
  const float* W1 = (const float*)d_in[2];
  const float* g1 = (const float*)d_in[4];
  const float* be1 = (const float*)d_in[5];
  const float* W2 = (const float*)d_in[6];
  const float* g2 = (const float*)d_in[8];
  const float* be2 = (const float*)d_in[9];
  const float* W3 = (const float*)d_in[10];
  const float* g3 = (const float*)d_in[12];
  const float* be3 = (const float*)d_in[13];
  float* out = (float*)d_out;

  char* ws = (char*)d_ws;
  unsigned short* y   = (unsigned short*)ws;               // 4 MB
  unsigned short* u   = (unsigned short*)(ws + (4u << 20));  // 4 MB
  unsigned short* v   = (unsigned short*)(ws + (8u << 20));  // 4 MB
  unsigned short* mnb = (unsigned short*)(ws + (12u << 20)); // 4 MB
  unsigned short* mxb = (unsigned short*)(ws + (16u << 20)); // 4 MB
  float* h3           = (float*)(ws + (20u << 20));          // 8 MB
  unsigned short* Wbf = (unsigned short*)(ws + (28u << 20)); // 16 KB (W2,W3)
  float* stats        = (float*)(ws + (28u << 20) + (64u << 10)); // 3*NREP*128 floats
  float* S1 = stats;
  float* S2 = stats + NREP * 128;
  float* S3 = stats + 2 * NREP * 128;

  hipMemsetAsync(stats, 0, 3 * NREP * 128 * sizeof(float), stream);
  prep<<<544, 256, 0, stream>>>(x, W1, W2, W3, y, Wbf);
  p1_stats<<<1024, 256, 0, stream>>>(y, idx, S1);
  p1b_uv<<<512, 256, 0, stream>>>(y, g1, be1, S1, u, v);
  p2_main<<<2048, 256, 0, stream>>>(u, v, idx, Wbf, mnb, mxb, S2);
  p3_gemm3<<<512, 256, 0, stream>>>(Wbf + 4096, mnb, mxb, g2, be2, S2, h3, S3);
  k4_out<<<512, 256, 0, stream>>>(h3, g3, be3, out, S3);
}

// Round 4
// 140.920 us; speedup vs baseline: 1.5338x; 1.0459x over previous
//
#include <hip/hip_runtime.h>

// Problem constants
#define EPSBN 1e-5f
#define CNT1 524288.0f   // B*N*K
#define CNT3 32768.0f    // B*N
#define NREP 16          // stats replicas (atomic spread)

typedef short v8s __attribute__((ext_vector_type(8)));
typedef float v16f __attribute__((ext_vector_type(16)));

__device__ __forceinline__ unsigned short f2bf(float f) {
  union { float f; unsigned u; } v; v.f = f;
  unsigned u = v.u;
  u += 0x7fffu + ((u >> 16) & 1u);   // RNE
  return (unsigned short)(u >> 16);
}
__device__ __forceinline__ unsigned pack2bf(float a, float b) {
  return (unsigned)f2bf(a) | ((unsigned)f2bf(b) << 16);
}
__device__ __forceinline__ float bflo(unsigned u) {
  union { unsigned u; float f; } v; v.u = u << 16; return v.f;
}
__device__ __forceinline__ float bfhi(unsigned u) {
  union { unsigned u; float f; } v; v.u = u & 0xffff0000u; return v.f;
}

// ---------------------------------------------------------------------------
// prep: y = W1 * x  (per point), y stored bf16 (B*N,64).
// Block = one (batch, 64-point) tile. Transpose x into LDS bf16, MFMA.
// ---------------------------------------------------------------------------
__global__ __launch_bounds__(256) void prep(
    const float* __restrict__ x, const float* __restrict__ W1,
    unsigned short* __restrict__ y) {
  __shared__ unsigned short ldsX[64 * 72];  // [point][ch], pad 72
  int blk = blockIdx.x, t = threadIdx.x;
  int b = blk >> 6, n0 = (blk & 63) << 6;
  int tn = t & 63, cg = t >> 6;
#pragma unroll
  for (int i = 0; i < 16; ++i) {
    int c = cg * 16 + i;
    ldsX[tn * 72 + c] = f2bf(x[(((size_t)(b * 64 + c)) << 12) + n0 + tn]);
  }
  __syncthreads();
  int lane = t & 63, w = t >> 6;
  int l31 = lane & 31, lh = lane >> 5;
  int ot = w & 1, ph = w >> 1;   // o-tile, point-half
  int o = ot * 32 + l31;
  v16f acc;
#pragma unroll
  for (int i = 0; i < 16; ++i) acc[i] = 0.f;
#pragma unroll
  for (int ks = 0; ks < 4; ++ks) {
    const float* wrow = W1 + o * 64 + ks * 16 + lh * 8;
    float4 wa = *((const float4*)wrow);
    float4 wb = *((const float4*)(wrow + 4));
    v8s wf; unsigned* wu = (unsigned*)&wf;
    wu[0] = pack2bf(wa.x, wa.y); wu[1] = pack2bf(wa.z, wa.w);
    wu[2] = pack2bf(wb.x, wb.y); wu[3] = pack2bf(wb.z, wb.w);
    v8s af = *((const v8s*)&ldsX[(ph * 32 + l31) * 72 + ks * 16 + lh * 8]);
    acc = __builtin_amdgcn_mfma_f32_32x32x16_bf16(af, wf, acc, 0, 0, 0);
  }
#pragma unroll
  for (int i = 0; i < 16; ++i) {
    int row = (i & 3) + ((i >> 2) << 3) + (lh << 2);
    int pt = (b << 12) + n0 + ph * 32 + row;
    y[pt * 64 + o] = f2bf(acc[i]);
  }
}

// ---------------------------------------------------------------------------
// p1: stats1 = sum/sumsq of (y_j - y_i) over all edges. Pure gather, no MFMA.
// Lane = (edge-in-8, 8-ch chunk). Batch pinned to XCD via blk&7.
// ---------------------------------------------------------------------------
__global__ __launch_bounds__(256) void p1_stats(
    const unsigned short* __restrict__ y, const int* __restrict__ idx,
    float* __restrict__ S1) {
  __shared__ float bs[64], bq[64];
  int t = threadIdx.x;
  if (t < 64) { bs[t] = 0.f; bq[t] = 0.f; }
  __syncthreads();
  int blk = blockIdx.x;
  int batch = blk & 7, bi = blk >> 3;       // bi 0..127
  int w = t >> 6, lane = t & 63;
  int ch = (lane & 7) << 3, eg = lane >> 3;
  int ebase = (batch << 16) + bi * 512 + w * 128;
  float ss[8], sq[8];
#pragma unroll
  for (int k = 0; k < 8; ++k) { ss[k] = 0.f; sq[k] = 0.f; }
  for (int it = 0; it < 16; ++it) {
    int p = ebase + it * 8 + eg;
    int j = idx[p];
    int site = p >> 4;
    uint4 uj = *((const uint4*)(y + (((size_t)((batch << 12) + j)) << 6) + ch));
    uint4 ui = *((const uint4*)(y + (((size_t)site) << 6) + ch));
    const unsigned* aj = (const unsigned*)&uj;
    const unsigned* ai = (const unsigned*)&ui;
#pragma unroll
    for (int d = 0; d < 4; ++d) {
      float d0 = bflo(aj[d]) - bflo(ai[d]);
      float d1 = bfhi(aj[d]) - bfhi(ai[d]);
      ss[2 * d] += d0; sq[2 * d] += d0 * d0;
      ss[2 * d + 1] += d1; sq[2 * d + 1] += d1 * d1;
    }
  }
#pragma unroll
  for (int k = 0; k < 8; ++k) {
    ss[k] += __shfl_xor(ss[k], 8);  sq[k] += __shfl_xor(sq[k], 8);
    ss[k] += __shfl_xor(ss[k], 16); sq[k] += __shfl_xor(sq[k], 16);
    ss[k] += __shfl_xor(ss[k], 32); sq[k] += __shfl_xor(sq[k], 32);
  }
  if (lane < 8) {
#pragma unroll
    for (int k = 0; k < 8; ++k) {
      atomicAdd(&bs[ch + k], ss[k]);
      atomicAdd(&bq[ch + k], sq[k]);
    }
  }
  __syncthreads();
  int rep = (blk >> 3) & (NREP - 1);
  if (t < 64) atomicAdd(&S1[rep * 128 + t], bs[t]);
  else if (t < 128) atomicAdd(&S1[rep * 128 + t], bq[t - 64]);
}

// ---------------------------------------------------------------------------
// p2: edge = relu(a1*(y_j - y_i) + c1) built directly as MFMA A-frags (BN1
// folded inline via LDS-broadcast a/c), GEMM2 (W2 cast in-register from fp32),
// stats2, per-site min/max over K=16 -> mnb/mxb (bf16).
// 512 blocks x 4 waves x 8 tiles (32 edges each).
// ---------------------------------------------------------------------------
__global__ __launch_bounds__(256) void p2_main(
    const unsigned short* __restrict__ y, const int* __restrict__ idx,
    const float* __restrict__ W2f,
    const float* __restrict__ g1, const float* __restrict__ be1,
    const float* __restrict__ S1,
    unsigned short* __restrict__ mnb, unsigned short* __restrict__ mxb,
    float* __restrict__ S2) {
  __shared__ float bs[64], bq[64];
  __shared__ __align__(16) float lA[64];
  __shared__ __align__(16) float lC[64];
  int t = threadIdx.x;
  if (t < 64) {
    bs[t] = 0.f; bq[t] = 0.f;
    float s = 0.f, q = 0.f;
#pragma unroll
    for (int r = 0; r < NREP; ++r) { s += S1[r * 128 + t]; q += S1[r * 128 + 64 + t]; }
    float mean = s / CNT1;
    float var = q / CNT1 - mean * mean;
    float a = g1[t] * rsqrtf(var + EPSBN);
    lA[t] = a; lC[t] = be1[t] - mean * a;
  }
  __syncthreads();
  int blk = blockIdx.x;
  int batch = blk & 7, bi = blk >> 3;   // bi 0..63
  int w = t >> 6, lane = t & 63;
  int l31 = lane & 31, lh = lane >> 5;
  // W2 bf16 fragments cast in-register from fp32 (L2-hit after first blocks)
  v8s w2[2][4];
#pragma unroll
  for (int s = 0; s < 2; ++s)
#pragma unroll
    for (int ks = 0; ks < 4; ++ks) {
      const float* wr = W2f + (s * 32 + l31) * 64 + ks * 16 + lh * 8;
      float4 wa = *((const float4*)wr);
      float4 wb = *((const float4*)(wr + 4));
      unsigned* wu = (unsigned*)&w2[s][ks];
      wu[0] = pack2bf(wa.x, wa.y); wu[1] = pack2bf(wa.z, wa.w);
      wu[2] = pack2bf(wb.x, wb.y); wu[3] = pack2bf(wb.z, wb.w);
    }
  float ss0 = 0.f, sq0 = 0.f, ss1 = 0.f, sq1 = 0.f;
  for (int it = 0; it < 8; ++it) {
    int tile = bi * 32 + w * 8 + it;            // 0..2047 within batch
    int p = (batch << 16) + (tile << 5) + l31;
    int j = idx[p];
    int site = p >> 4;
    const unsigned short* yj = y + (((size_t)((batch << 12) + j)) << 6) + lh * 8;
    const unsigned short* yi = y + (((size_t)site) << 6) + lh * 8;
    v16f b0, b1;
#pragma unroll
    for (int i = 0; i < 16; ++i) { b0[i] = 0.f; b1[i] = 0.f; }
#pragma unroll
    for (int ks = 0; ks < 4; ++ks) {
      uint4 uj = *((const uint4*)(yj + ks * 16));
      uint4 ui = *((const uint4*)(yi + ks * 16));
      float4 a0 = *((const float4*)&lA[ks * 16 + lh * 8]);
      float4 a1 = *((const float4*)&lA[ks * 16 + lh * 8 + 4]);
      float4 c0 = *((const float4*)&lC[ks * 16 + lh * 8]);
      float4 c1 = *((const float4*)&lC[ks * 16 + lh * 8 + 4]);
      float av[8] = {a0.x, a0.y, a0.z, a0.w, a1.x, a1.y, a1.z, a1.w};
      float cv[8] = {c0.x, c0.y, c0.z, c0.w, c1.x, c1.y, c1.z, c1.w};
      const unsigned* jw = (const unsigned*)&uj;
      const unsigned* iw = (const unsigned*)&ui;
      v8s af; unsigned* au = (unsigned*)&af;
#pragma unroll
      for (int d = 0; d < 4; ++d) {
        float e0 = fmaxf((bflo(jw[d]) - bflo(iw[d])) * av[2 * d] + cv[2 * d], 0.f);
        float e1 = fmaxf((bfhi(jw[d]) - bfhi(iw[d])) * av[2 * d + 1] + cv[2 * d + 1], 0.f);
        au[d] = pack2bf(e0, e1);
      }
      b0 = __builtin_amdgcn_mfma_f32_32x32x16_bf16(af, w2[0][ks], b0, 0, 0, 0);
      b1 = __builtin_amdgcn_mfma_f32_32x32x16_bf16(af, w2[1][ks], b1, 0, 0, 0);
    }
    float mx00 = b0[0], mn00 = b0[0], mx01 = b0[8], mn01 = b0[8];
    float mx10 = b1[0], mn10 = b1[0], mx11 = b1[8], mn11 = b1[8];
#pragma unroll
    for (int i = 0; i < 16; ++i) {
      ss0 += b0[i]; sq0 += b0[i] * b0[i];
      ss1 += b1[i]; sq1 += b1[i] * b1[i];
    }
#pragma unroll
    for (int i = 1; i < 8; ++i) {
      mx00 = fmaxf(mx00, b0[i]);     mn00 = fminf(mn00, b0[i]);
      mx01 = fmaxf(mx01, b0[8 + i]); mn01 = fminf(mn01, b0[8 + i]);
      mx10 = fmaxf(mx10, b1[i]);     mn10 = fminf(mn10, b1[i]);
      mx11 = fmaxf(mx11, b1[8 + i]); mn11 = fminf(mn11, b1[8 + i]);
    }
    mx00 = fmaxf(mx00, __shfl_xor(mx00, 32)); mn00 = fminf(mn00, __shfl_xor(mn00, 32));
    mx01 = fmaxf(mx01, __shfl_xor(mx01, 32)); mn01 = fminf(mn01, __shfl_xor(mn01, 32));
    mx10 = fmaxf(mx10, __shfl_xor(mx10, 32)); mn10 = fminf(mn10, __shfl_xor(mn10, 32));
    mx11 = fmaxf(mx11, __shfl_xor(mx11, 32)); mn11 = fminf(mn11, __shfl_xor(mn11, 32));
    int s2 = (batch << 12) + (tile << 1);
    if (lh == 0) {
      mnb[(size_t)(s2 + 0) * 64 + l31] = f2bf(mn00);
      mnb[(size_t)(s2 + 1) * 64 + l31] = f2bf(mn01);
      mnb[(size_t)(s2 + 0) * 64 + 32 + l31] = f2bf(mn10);
      mnb[(size_t)(s2 + 1) * 64 + 32 + l31] = f2bf(mn11);
    } else {
      mxb[(size_t)(s2 + 0) * 64 + l31] = f2bf(mx00);
      mxb[(size_t)(s2 + 1) * 64 + l31] = f2bf(mx01);
      mxb[(size_t)(s2 + 0) * 64 + 32 + l31] = f2bf(mx10);
      mxb[(size_t)(s2 + 1) * 64 + 32 + l31] = f2bf(mx11);
    }
  }
  ss0 += __shfl_xor(ss0, 32); sq0 += __shfl_xor(sq0, 32);
  ss1 += __shfl_xor(ss1, 32); sq1 += __shfl_xor(sq1, 32);
  if (lh == 0) {
    atomicAdd(&bs[l31], ss0); atomicAdd(&bq[l31], sq0);
    atomicAdd(&bs[32 + l31], ss1); atomicAdd(&bq[32 + l31], sq1);
  }
  __syncthreads();
  int rep = blk & (NREP - 1);
  if (t < 64) atomicAdd(&S2[rep * 128 + t], bs[t]);
  else if (t < 128) atomicAdd(&S2[rep * 128 + t], bq[t - 64]);
}

// ---------------------------------------------------------------------------
// p3: BN2 via sign-select on bf16 min/max, ReLU, GEMM3 (W3 cast in-register)
// -> h3 fp32, stats3
// ---------------------------------------------------------------------------
__global__ __launch_bounds__(256, 2) void p3_gemm3(
    const float* __restrict__ W3f,
    const unsigned short* __restrict__ mnb, const unsigned short* __restrict__ mxb,
    const float* __restrict__ g2, const float* __restrict__ be2,
    const float* __restrict__ S2, float* __restrict__ h3, float* __restrict__ S3) {
  __shared__ uint4 ldsA[64 * 9];
  __shared__ float bs[64], bq[64], lA[64], lC[64];
  int t = threadIdx.x;
  if (t < 64) {
    bs[t] = 0.f; bq[t] = 0.f;
    float s = 0.f, q = 0.f;
#pragma unroll
    for (int r = 0; r < NREP; ++r) { s += S2[r * 128 + t]; q += S2[r * 128 + 64 + t]; }
    float mean = s / CNT1;
    float var = q / CNT1 - mean * mean;
    float a = g2[t] * rsqrtf(var + EPSBN);
    lA[t] = a; lC[t] = be2[t] - mean * a;
  }
  __syncthreads();
  int lane = t & 63, wid = t >> 6;
  int rb = wid & 1, ctile = wid >> 1;
  int l31 = lane & 31, lh = lane >> 5;
  int o = ctile * 32 + l31;
  v8s wf[4];
#pragma unroll
  for (int ks = 0; ks < 4; ++ks) {
    const float* wr = W3f + o * 64 + ks * 16 + lh * 8;
    float4 wa = *((const float4*)wr);
    float4 wb = *((const float4*)(wr + 4));
    unsigned* wu = (unsigned*)&wf[ks];
    wu[0] = pack2bf(wa.x, wa.y); wu[1] = pack2bf(wa.z, wa.w);
    wu[2] = pack2bf(wb.x, wb.y); wu[3] = pack2bf(wb.z, wb.w);
  }
  int r = t >> 2, q = t & 3;
  int arow = rb * 32 + l31;
  int s0 = blockIdx.x << 6;
  {
    int site = s0 + r;
    const uint4* mnp = (const uint4*)(mnb + (size_t)site * 64 + q * 16);
    const uint4* mxp = (const uint4*)(mxb + (size_t)site * 64 + q * 16);
    uint4 m0 = mnp[0], m1 = mnp[1], x0 = mxp[0], x1 = mxp[1];
    uint4 ch2[2];
    unsigned* cu = (unsigned*)ch2;
#pragma unroll
    for (int d = 0; d < 8; ++d) {
      unsigned md = (d < 4) ? ((const unsigned*)&m0)[d] : ((const unsigned*)&m1)[d - 4];
      unsigned xd = (d < 4) ? ((const unsigned*)&x0)[d] : ((const unsigned*)&x1)[d - 4];
      int c = q * 16 + 2 * d;
      float a0 = lA[c], a1 = lA[c + 1];
      float s0v = (a0 > 0.f) ? bflo(xd) : bflo(md);
      float s1v = (a1 > 0.f) ? bfhi(xd) : bfhi(md);
      float v0 = fmaxf(a0 * s0v + lC[c], 0.f);
      float v1 = fmaxf(a1 * s1v + lC[c + 1], 0.f);
      cu[d] = pack2bf(v0, v1);
    }
    ldsA[r * 9 + q * 2 + 0] = ch2[0];
    ldsA[r * 9 + q * 2 + 1] = ch2[1];
  }
  __syncthreads();
  v16f acc;
#pragma unroll
  for (int i = 0; i < 16; ++i) acc[i] = 0.f;
#pragma unroll
  for (int ks = 0; ks < 4; ++ks) {
    v8s a = *((const v8s*)&ldsA[arow * 9 + ks * 2 + lh]);
    acc = __builtin_amdgcn_mfma_f32_32x32x16_bf16(a, wf[ks], acc, 0, 0, 0);
  }
  float ssum = 0.f, ssq = 0.f;
#pragma unroll
  for (int i = 0; i < 16; ++i) {
    float vv = acc[i];
    ssum += vv; ssq += vv * vv;
    int row = (i & 3) + ((i >> 2) << 3) + (lh << 2);
    h3[(((size_t)(s0 + rb * 32 + row)) << 6) + o] = vv;
  }
  ssum += __shfl_xor(ssum, 32);
  ssq += __shfl_xor(ssq, 32);
  if (lh == 0) { atomicAdd(&bs[o], ssum); atomicAdd(&bq[o], ssq); }
  __syncthreads();
  int rep = blockIdx.x & (NREP - 1);
  if (t < 64) atomicAdd(&S3[rep * 128 + t], bs[t]);
  else if (t < 128) atomicAdd(&S3[rep * 128 + t], bq[t - 64]);
}

// ---------------------------------------------------------------------------
// k4: BN3+ReLU, transpose (B,N,E)->(B,E,N), write out
// ---------------------------------------------------------------------------
__global__ void k4_out(const float* __restrict__ h3,
                       const float* __restrict__ g3, const float* __restrict__ be3,
                       float* __restrict__ out, const float* __restrict__ S3) {
  __shared__ float lA[64], lC[64];
  __shared__ float tile[64][65];
  int t = threadIdx.x;
  if (t < 64) {
    float s = 0.f, q = 0.f;
#pragma unroll
    for (int r = 0; r < NREP; ++r) { s += S3[r * 128 + t]; q += S3[r * 128 + 64 + t]; }
    float mean = s / CNT3;
    float var = q / CNT3 - mean * mean;
    float a = g3[t] * rsqrtf(var + EPSBN);
    lA[t] = a; lC[t] = be3[t] - mean * a;
  }
  __syncthreads();
  int blk = blockIdx.x;
  int b = blk >> 6, n0 = (blk & 63) << 6;
  int r = t >> 2, q = t & 3;
  const float4* hp = (const float4*)(h3 + (((size_t)((b << 12) + n0 + r)) << 6)) + q * 4;
#pragma unroll
  for (int ii = 0; ii < 4; ++ii) {
    float4 v = hp[ii];
    int c = q * 16 + ii * 4;
    tile[c + 0][r] = fmaxf(v.x * lA[c + 0] + lC[c + 0], 0.f);
    tile[c + 1][r] = fmaxf(v.y * lA[c + 1] + lC[c + 1], 0.f);
    tile[c + 2][r] = fmaxf(v.z * lA[c + 2] + lC[c + 2], 0.f);
    tile[c + 3][r] = fmaxf(v.w * lA[c + 3] + lC[c + 3], 0.f);
  }
  __syncthreads();
  int oo = t >> 2, seg = t & 3;
  float4* dst = (float4*)(out + (((size_t)(b * 64 + oo)) << 12) + n0 + seg * 16);
#pragma unroll
  for (int ii = 0; ii < 4; ++ii) {
    float4 v;
    v.x = tile[oo][seg * 16 + ii * 4 + 0];
    v.y = tile[oo][seg * 16 + ii * 4 + 1];
    v.z = tile[oo][seg * 16 + ii * 4 + 2];
    v.w = tile[oo][seg * 16 + ii * 4 + 3];
    dst[ii] = v;
  }
}

// ---------------------------------------------------------------------------
extern "C" void kernel_launch(void* const* d_in, const int* in_sizes, int n_in,
                              void* d_out, int out_size, void* d_ws, size_t ws_size,
                              hipStream_t stream) {
  const float* x = (const float*)d_in[0];
  const int* idx = (const int*)d_in[1];
  const float* W1 = (const float*)d_in[2];
  const float* g1 = (const float*)d_in[4];
  const float* be1 = (const float*)d_in[5];
  const float* W2 = (const float*)d_in[6];
  const float* g2 = (const float*)d_in[8];
  const float* be2 = (const float*)d_in[9];
  const float* W3 = (const float*)d_in[10];
  const float* g3 = (const float*)d_in[12];
  const float* be3 = (const float*)d_in[13];
  float* out = (float*)d_out;

  char* ws = (char*)d_ws;
  unsigned short* y   = (unsigned short*)ws;                 // 4 MB
  unsigned short* mnb = (unsigned short*)(ws + (4u << 20));  // 4 MB
  unsigned short* mxb = (unsigned short*)(ws + (8u << 20));  // 4 MB
  float* h3           = (float*)(ws + (12u << 20));          // 8 MB
  float* stats        = (float*)(ws + (20u << 20));          // 3*NREP*128 floats
  float* S1 = stats;
  float* S2 = stats + NREP * 128;
  float* S3 = stats + 2 * NREP * 128;

  hipMemsetAsync(stats, 0, 3 * NREP * 128 * sizeof(float), stream);
  prep<<<512, 256, 0, stream>>>(x, W1, y);
  p1_stats<<<1024, 256, 0, stream>>>(y, idx, S1);
  p2_main<<<512, 256, 0, stream>>>(y, idx, W2, g1, be1, S1, mnb, mxb, S2);
  p3_gemm3<<<512, 256, 0, stream>>>(W3, mnb, mxb, g2, be2, S2, h3, S3);
  k4_out<<<512, 256, 0, stream>>>(h3, g3, be3, out, S3);
}